// Round 7
// baseline (588.923 us; speedup 1.0000x reference)
//
#include <hip/hip_runtime.h>
#include <math.h>

// ---------------------------------------------------------------------------
// DynamicGNN: GCN -> SAGE(mean) -> GAT(1 head) -> GCN(128->64)
// N=50000, E=1.6M, D=128, OUT=64, fp32 compute.
// v7: per-edge weights precomputed into interleaved (src, w) records —
//     GCN weight factorization (dinv_d pulled out of the sum), GAT alpha
//     written by attn_reduce (expf off the gather hot path). Gather inner
//     loop: 1 rec load + 1 H load + 2 unpack + 4 FMA per edge.
// ---------------------------------------------------------------------------

#define BUCKET_BITS 8
#define BUCKET_SZ   256
#define NBMAX       256

__device__ __forceinline__ float leaky02(float x) { return x > 0.0f ? x : 0.2f * x; }
__device__ __forceinline__ float bflo(unsigned u) { return __uint_as_float(u << 16); }
__device__ __forceinline__ float bfhi(unsigned u) { return __uint_as_float(u & 0xFFFF0000u); }
__device__ __forceinline__ unsigned short f2bf(float f) {
    unsigned u = __float_as_uint(f);
    u += 0x7FFFu + ((u >> 16) & 1u);   // round-to-nearest-even
    return (unsigned short)(u >> 16);
}

// ---------------- GEMM: C[n x NO] = A[n x 128] @ W[128 x NO] (+C if accum)
template<int NO, bool DOTS>
__global__ __launch_bounds__(256) void gemm_k(
    const float* __restrict__ A, const float* __restrict__ W,
    float* __restrict__ C, unsigned short* __restrict__ C16,
    const float* __restrict__ bias, int relu, int accum,
    const float* __restrict__ a_s, const float* __restrict__ a_d,
    float* __restrict__ as_, float* __restrict__ ad_, int n)
{
    constexpr int CHUNK = NO / 32;
    __shared__ float Ws[32 * NO];
    const int tid = threadIdx.x;
    const int row0 = blockIdx.x * 32;
    const int rb = ((tid >> 5) & 7) * 4;
    const int cb = tid & 31;

    int gr[4];
    bool valid[4];
#pragma unroll
    for (int i = 0; i < 4; i++) {
        int r = row0 + rb + i;
        valid[i] = (r < n);
        gr[i] = valid[i] ? r : (n - 1);
    }

    float acc[4][CHUNK];
#pragma unroll
    for (int i = 0; i < 4; i++)
#pragma unroll
        for (int c = 0; c < CHUNK; c++) acc[i][c] = 0.0f;

    const float4* A4 = (const float4*)A;
    for (int t = 0; t < 4; t++) {
        __syncthreads();
        const float4* Wt = (const float4*)(W + t * 32 * NO);
        for (int i = tid; i < 32 * NO / 4; i += 256) ((float4*)Ws)[i] = Wt[i];
        __syncthreads();
#pragma unroll
        for (int k4 = 0; k4 < 8; k4++) {
            float4 a4[4];
#pragma unroll
            for (int i = 0; i < 4; i++) a4[i] = A4[(size_t)gr[i] * 32 + t * 8 + k4];
#pragma unroll
            for (int kk = 0; kk < 4; kk++) {
                const int koff = k4 * 4 + kk;
                float wv[CHUNK];
#pragma unroll
                for (int c = 0; c < CHUNK; c++) wv[c] = Ws[koff * NO + cb * CHUNK + c];
                const float av[4] = {
                    kk == 0 ? a4[0].x : kk == 1 ? a4[0].y : kk == 2 ? a4[0].z : a4[0].w,
                    kk == 0 ? a4[1].x : kk == 1 ? a4[1].y : kk == 2 ? a4[1].z : a4[1].w,
                    kk == 0 ? a4[2].x : kk == 1 ? a4[2].y : kk == 2 ? a4[2].z : a4[2].w,
                    kk == 0 ? a4[3].x : kk == 1 ? a4[3].y : kk == 2 ? a4[3].z : a4[3].w };
#pragma unroll
                for (int i = 0; i < 4; i++)
#pragma unroll
                    for (int c = 0; c < CHUNK; c++)
                        acc[i][c] = fmaf(av[i], wv[c], acc[i][c]);
            }
        }
    }

    if (DOTS) {
        float asv[CHUNK], adv[CHUNK];
#pragma unroll
        for (int c = 0; c < CHUNK; c++) { asv[c] = a_s[cb * CHUNK + c]; adv[c] = a_d[cb * CHUNK + c]; }
#pragma unroll
        for (int i = 0; i < 4; i++) {
            float ps = 0.f, pd = 0.f;
#pragma unroll
            for (int c = 0; c < CHUNK; c++) {
                ps = fmaf(acc[i][c], asv[c], ps);
                pd = fmaf(acc[i][c], adv[c], pd);
            }
#pragma unroll
            for (int off = 16; off > 0; off >>= 1) {
                ps += __shfl_xor(ps, off);
                pd += __shfl_xor(pd, off);
            }
            if (cb == 0 && valid[i]) { as_[gr[i]] = ps; ad_[gr[i]] = pd; }
        }
    }

#pragma unroll
    for (int i = 0; i < 4; i++) {
        if (valid[i]) {
            const size_t base = (size_t)gr[i] * NO + cb * CHUNK;
            float vv[CHUNK];
            float prior[CHUNK];
            if (accum) {
                if constexpr (CHUNK == 4) { float4 p = *(const float4*)(C + base);
                    prior[0]=p.x; prior[1]=p.y; prior[2]=p.z; prior[3]=p.w; }
                else { float2 p = *(const float2*)(C + base); prior[0]=p.x; prior[1]=p.y; }
            }
#pragma unroll
            for (int c = 0; c < CHUNK; c++) {
                float v = acc[i][c];
                if (accum) v += prior[c];
                if (bias)  v += bias[cb * CHUNK + c];
                if (relu)  v = fmaxf(v, 0.0f);
                vv[c] = v;
            }
            if constexpr (CHUNK == 4) {
                float4 p; p.x=vv[0]; p.y=vv[1]; p.z=vv[2]; p.w=vv[3];
                *(float4*)(C + base) = p;
            } else {
                float2 p; p.x=vv[0]; p.y=vv[1];
                *(float2*)(C + base) = p;
            }
            if (C16) {
                if constexpr (CHUNK == 4) {
                    ushort4 q; q.x=f2bf(vv[0]); q.y=f2bf(vv[1]); q.z=f2bf(vv[2]); q.w=f2bf(vv[3]);
                    *(ushort4*)(C16 + base) = q;
                } else {
                    ushort2 q; q.x=f2bf(vv[0]); q.y=f2bf(vv[1]);
                    *(ushort2*)(C16 + base) = q;
                }
            }
        }
    }
}

// ---------------- CSR build (atomic-free on global data) ----------------
#define BH_CH 4096
__global__ __launch_bounds__(256) void bhist_k(const int* __restrict__ dst,
                                               int* __restrict__ btot, int nE) {
    __shared__ int lh[NBMAX];
    const int t = threadIdx.x;
    lh[t] = 0;
    __syncthreads();
    const int base = blockIdx.x * BH_CH;
#pragma unroll
    for (int j = 0; j < BH_CH / 256; j++) {
        int e = base + j * 256 + t;
        if (e < nE) atomicAdd(&lh[dst[e] >> BUCKET_BITS], 1);
    }
    __syncthreads();
    if (lh[t]) atomicAdd(&btot[t], lh[t]);
}

__global__ __launch_bounds__(256) void bscan_k(const int* __restrict__ btot,
                                               int* __restrict__ bofs,
                                               int* __restrict__ bcur, int nb) {
    __shared__ int sm[256];
    const int t = threadIdx.x;
    int v = (t < nb) ? btot[t] : 0;
    sm[t] = v;
    __syncthreads();
    for (int off = 1; off < 256; off <<= 1) {
        int tv = (t >= off) ? sm[t - off] : 0;
        __syncthreads();
        sm[t] += tv;
        __syncthreads();
    }
    if (t < nb) {
        int excl = sm[t] - v;
        bofs[t] = excl;
        bcur[t] = excl;
        if (t == nb - 1) bofs[nb] = sm[t];
    }
}

#define PART_CH 4096
__global__ __launch_bounds__(256) void part_k(
    const int* __restrict__ src, const int* __restrict__ dst,
    int* __restrict__ bcur, unsigned long long* __restrict__ part, int nE)
{
    __shared__ int cnt[NBMAX];
    __shared__ int cur[NBMAX];
    const int base = blockIdx.x * PART_CH;
    const int t = threadIdx.x;
    cnt[t] = 0;
    __syncthreads();
    int d[PART_CH / 256], s[PART_CH / 256];
#pragma unroll
    for (int j = 0; j < PART_CH / 256; j++) {
        int e = base + j * 256 + t;
        if (e < nE) {
            d[j] = dst[e]; s[j] = src[e];
            atomicAdd(&cnt[d[j] >> BUCKET_BITS], 1);
        } else d[j] = -1;
    }
    __syncthreads();
    {
        int c = cnt[t];
        cur[t] = c ? atomicAdd(&bcur[t], c) : 0;
    }
    __syncthreads();
#pragma unroll
    for (int j = 0; j < PART_CH / 256; j++) {
        if (d[j] >= 0) {
            int p = atomicAdd(&cur[d[j] >> BUCKET_BITS], 1);
            part[p] = ((unsigned long long)(unsigned)d[j] << 32) | (unsigned)s[j];
        }
    }
}

__global__ __launch_bounds__(256) void csr_k(
    const unsigned long long* __restrict__ part, const int* __restrict__ bofs,
    int* __restrict__ rowptr, int* __restrict__ srcs,
    float* __restrict__ dinv, float* __restrict__ invm, int n, int nE)
{
    __shared__ int lcnt[BUCKET_SZ];
    __shared__ int sm[BUCKET_SZ];
    __shared__ int lcur[BUCKET_SZ];
    const int b = blockIdx.x;
    const int t = threadIdx.x;
    const int base = bofs[b];
    const int cntE = bofs[b + 1] - base;

    lcnt[t] = 0;
    __syncthreads();
#pragma unroll 4
    for (int e = t; e < cntE; e += 256) {
        int dl = (int)(part[base + e] >> 32) & (BUCKET_SZ - 1);
        atomicAdd(&lcnt[dl], 1);
    }
    __syncthreads();
    int v = lcnt[t];
    sm[t] = v;
    __syncthreads();
    for (int off = 1; off < 256; off <<= 1) {
        int tv = (t >= off) ? sm[t - off] : 0;
        __syncthreads();
        sm[t] += tv;
        __syncthreads();
    }
    const int excl = sm[t] - v;
    const int node = (b << BUCKET_BITS) + t;
    if (node < n) {
        rowptr[node] = base + excl;
        float dg = (float)v;
        dinv[node] = rsqrtf(dg + 1.0f);
        invm[node] = 1.0f / fmaxf(dg, 1.0f);
        if (node == n - 1) rowptr[n] = nE;
    }
    lcur[t] = excl;
    __syncthreads();
#pragma unroll 4
    for (int e = t; e < cntE; e += 256) {
        unsigned long long w = part[base + e];
        int dl = (int)(w >> 32) & (BUCKET_SZ - 1);
        int pos = atomicAdd(&lcur[dl], 1);
        srcs[base + pos] = (int)(unsigned)w;
    }
}

// build GCN edge records: recA[e] = (src, dinv[src])
__global__ void wfill_k(const int* __restrict__ srcs, const float* __restrict__ dinv,
                        uint2* __restrict__ recA, int nE) {
    int e = blockIdx.x * blockDim.x + threadIdx.x;
    if (e < nE) {
        int s = srcs[e];
        recA[e] = make_uint2((unsigned)s, __float_as_uint(dinv[s]));
    }
}

// ---------------- record-based bf16 gather ----------------
// MODE 0: SAGE mean (srcs only, w=1, scale by invm). MODE 1: GCN + bias + ReLU
// (recA weights, end-scale by dinv_d; +bf16 mirror). MODE 2: GAT + bias + ReLU
// (recG alpha weights, self-alpha in den_). MODE 3: GCN out, no ReLU.
template<int F, int MODE>
__global__ __launch_bounds__(256) void gatherbf_k(
    const unsigned short* __restrict__ H16, const float* __restrict__ Hf,
    float* __restrict__ out, unsigned short* __restrict__ out16,
    const int* __restrict__ rowptr, const int* __restrict__ srcs,
    const uint2* __restrict__ REC, const float* __restrict__ dinv,
    const float* __restrict__ den_, const float* __restrict__ bias, int n)
{
    constexpr int LPN = F / 4;
    constexpr int NPB = 256 / LPN;
    const int node = blockIdx.x * NPB + (int)(threadIdx.x / LPN);
    const int lane = (int)(threadIdx.x & (LPN - 1));
    if (node >= n) return;
    const int beg = rowptr[node], end = rowptr[node + 1];

    const uint2* __restrict__ H2 = (const uint2*)H16;
    float4 acc = make_float4(0.f, 0.f, 0.f, 0.f);

    int k = beg;
    for (; k + 8 <= end; k += 8) {
        unsigned sidx[8]; float wv[8];
        if (MODE == 0) {
#pragma unroll
            for (int j = 0; j < 8; j++) { sidx[j] = (unsigned)srcs[k + j]; wv[j] = 1.0f; }
        } else {
#pragma unroll
            for (int j = 0; j < 8; j++) {
                uint2 rc = REC[k + j];
                sidx[j] = rc.x; wv[j] = __uint_as_float(rc.y);
            }
        }
        uint2 h[8];
#pragma unroll
        for (int j = 0; j < 8; j++) h[j] = H2[(size_t)sidx[j] * LPN + lane];
#pragma unroll
        for (int j = 0; j < 8; j++) {
            if (MODE == 0) {
                acc.x += bflo(h[j].x); acc.y += bfhi(h[j].x);
                acc.z += bflo(h[j].y); acc.w += bfhi(h[j].y);
            } else {
                acc.x = fmaf(wv[j], bflo(h[j].x), acc.x);
                acc.y = fmaf(wv[j], bfhi(h[j].x), acc.y);
                acc.z = fmaf(wv[j], bflo(h[j].y), acc.z);
                acc.w = fmaf(wv[j], bfhi(h[j].y), acc.w);
            }
        }
    }
    if (k < end) {
        unsigned sidx[8]; float wv[8]; bool act[8];
#pragma unroll
        for (int j = 0; j < 8; j++) {
            int kk = k + j;
            act[j] = (kk < end);
            int idx = act[j] ? kk : (end - 1);
            if (MODE == 0) { sidx[j] = (unsigned)srcs[idx]; wv[j] = act[j] ? 1.0f : 0.0f; }
            else {
                uint2 rc = REC[idx];
                sidx[j] = rc.x; wv[j] = act[j] ? __uint_as_float(rc.y) : 0.0f;
            }
        }
        uint2 h[8];
#pragma unroll
        for (int j = 0; j < 8; j++) h[j] = H2[(size_t)sidx[j] * LPN + lane];
#pragma unroll
        for (int j = 0; j < 8; j++) {
            acc.x = fmaf(wv[j], bflo(h[j].x), acc.x);
            acc.y = fmaf(wv[j], bfhi(h[j].x), acc.y);
            acc.z = fmaf(wv[j], bflo(h[j].y), acc.z);
            acc.w = fmaf(wv[j], bfhi(h[j].y), acc.w);
        }
    }

    const size_t oi = (size_t)node * LPN + lane;
    float4 r = acc;
    if (MODE == 0) {
        float sc = dinv[node];            // invm passed via dinv arg
        r.x *= sc; r.y *= sc; r.z *= sc; r.w *= sc;
    } else {
        float4 self = ((const float4*)Hf)[oi];
        float4 bv = ((const float4*)bias)[lane];
        float sw, os;
        if (MODE == 2) { sw = den_[node]; os = 1.0f; }            // self-alpha
        else { float dv = dinv[node]; sw = dv * dv; os = dv; }    // GCN factorized
        r.x = os * r.x + sw * self.x + bv.x;
        r.y = os * r.y + sw * self.y + bv.y;
        r.z = os * r.z + sw * self.z + bv.z;
        r.w = os * r.w + sw * self.w + bv.w;
        if (MODE != 3) {
            r.x = fmaxf(r.x, 0.f); r.y = fmaxf(r.y, 0.f);
            r.z = fmaxf(r.z, 0.f); r.w = fmaxf(r.w, 0.f);
        }
    }
    ((float4*)out)[oi] = r;
    if (MODE == 1) {
        ushort4 q; q.x = f2bf(r.x); q.y = f2bf(r.y); q.z = f2bf(r.z); q.w = f2bf(r.w);
        ((ushort4*)out16)[oi] = q;
    }
}

// ---------------- GAT softmax: writes recG[e]=(src,alpha), den_[node]=self-alpha
__global__ __launch_bounds__(256) void attn_reduce_k(
    const int* __restrict__ rowptr, const int* __restrict__ srcs,
    const float* __restrict__ as_, const float* __restrict__ ad_,
    uint2* __restrict__ recG, float* __restrict__ den_, int n)
{
    int node = blockIdx.x * 4 + (int)(threadIdx.x >> 6);
    int lane = threadIdx.x & 63;
    if (node >= n) return;
    int beg = rowptr[node], end = rowptr[node + 1];
    float ad_d = ad_[node];
    float self_e = leaky02(as_[node] + ad_d);
    float mx = self_e;
    for (int k = beg + lane; k < end; k += 64)
        mx = fmaxf(mx, leaky02(as_[srcs[k]] + ad_d));
    for (int off = 32; off > 0; off >>= 1) mx = fmaxf(mx, __shfl_xor(mx, off, 64));
    float sum = (lane == 0) ? expf(self_e - mx) : 0.0f;
    for (int k = beg + lane; k < end; k += 64)
        sum += expf(leaky02(as_[srcs[k]] + ad_d) - mx);
    for (int off = 32; off > 0; off >>= 1) sum += __shfl_xor(sum, off, 64);
    float rden = 1.0f / sum;
    for (int k = beg + lane; k < end; k += 64) {
        int s = srcs[k];
        float a = expf(leaky02(as_[s] + ad_d) - mx) * rden;
        recG[k] = make_uint2((unsigned)s, __float_as_uint(a));
    }
    if (lane == 0) den_[node] = expf(self_e - mx) * rden;
}

// ---------------------------------------------------------------------------
extern "C" void kernel_launch(void* const* d_in, const int* in_sizes, int n_in,
                              void* d_out, int out_size, void* d_ws, size_t ws_size,
                              hipStream_t stream)
{
    const float* x   = (const float*)d_in[0];
    const int*   ei  = (const int*)d_in[1];
    const float* W1  = (const float*)d_in[2];
    const float* b1  = (const float*)d_in[3];
    const float* Wl  = (const float*)d_in[4];
    const float* Wr  = (const float*)d_in[5];
    const float* bs  = (const float*)d_in[6];
    const float* Wg  = (const float*)d_in[7];
    const float* a_s = (const float*)d_in[8];
    const float* a_d = (const float*)d_in[9];
    const float* bg  = (const float*)d_in[10];
    const float* Wo  = (const float*)d_in[11];
    const float* bo  = (const float*)d_in[12];

    const int n  = in_sizes[0] / 128;
    const int nE = in_sizes[1] / 2;
    const int* src = ei;
    const int* dst = ei + nE;

    char* w = (char*)d_ws;
    auto alloc = [&](size_t bytes) { char* p = w; w += (bytes + 255) & ~(size_t)255; return p; };
    float* B0     = (float*)alloc((size_t)n * 128 * 4);
    float* B1     = (float*)alloc((size_t)n * 128 * 4);   // also CSR partition scratch
    float* B2     = (float*)alloc((size_t)n * 128 * 4);
    unsigned short* M16a = (unsigned short*)alloc((size_t)n * 128 * 2);
    unsigned short* M16b = (unsigned short*)alloc((size_t)n * 128 * 2);
    int*   srcs   = (int*)alloc((size_t)nE * 4);
    uint2* recA   = (uint2*)alloc((size_t)nE * 8);
    uint2* recG   = (uint2*)alloc((size_t)nE * 8);
    int*   rowptr = (int*)alloc((size_t)(n + 1) * 4);
    int*   btot   = (int*)alloc(NBMAX * 4);
    int*   bofs   = (int*)alloc((NBMAX + 1) * 4);
    int*   bcur   = (int*)alloc(NBMAX * 4);
    float* dinv   = (float*)alloc((size_t)n * 4);
    float* invm   = (float*)alloc((size_t)n * 4);
    float* as_    = (float*)alloc((size_t)n * 4);
    float* ad_    = (float*)alloc((size_t)n * 4);
    float* den_   = (float*)alloc((size_t)n * 4);
    unsigned long long* part = (unsigned long long*)B1;

    const int TB = 256;
    auto cdiv = [](long long a, long long b) { return (int)((a + b - 1) / b); };
    const int nb     = cdiv(n, BUCKET_SZ);
    const int gBh    = cdiv(nE, BH_CH);
    const int gPart  = cdiv(nE, PART_CH);
    const int gE     = cdiv(nE, TB);
    const int gGemm  = cdiv(n, 32);
    const int gGa128 = cdiv(n, 8);
    const int gGa64  = cdiv(n, 16);
    const int gQuad  = cdiv(n, 4);

    // ---- CSR build: bucket hist -> scan -> partition -> per-bucket LDS CSR
    hipMemsetAsync(btot, 0, NBMAX * 4, stream);
    bhist_k<<<gBh, TB, 0, stream>>>(dst, btot, nE);
    bscan_k<<<1, 256, 0, stream>>>(btot, bofs, bcur, nb);
    part_k<<<gPart, TB, 0, stream>>>(src, dst, bcur, part, nE);
    csr_k<<<nb, TB, 0, stream>>>(part, bofs, rowptr, srcs, dinv, invm, n, nE);
    wfill_k<<<gE, TB, 0, stream>>>(srcs, dinv, recA, nE);

    // ---- Layer 1: GCN(128->128) + ReLU -> B2 (+M16b)
    gemm_k<128, false><<<gGemm, TB, 0, stream>>>(x, W1, B0, M16a, nullptr, 0, 0,
                                                 nullptr, nullptr, nullptr, nullptr, n);
    gatherbf_k<128, 1><<<gGa128, TB, 0, stream>>>(M16a, B0, B2, M16b, rowptr, srcs, recA,
                                                  dinv, nullptr, b1, n);

    // ---- Layer 2: SAGE(mean) + ReLU -> B1
    gatherbf_k<128, 0><<<gGa128, TB, 0, stream>>>(M16b, nullptr, B0, nullptr, rowptr, srcs, nullptr,
                                                  invm, nullptr, nullptr, n);
    gemm_k<128, false><<<gGemm, TB, 0, stream>>>(B0, Wl, B1, nullptr, nullptr, 0, 0,
                                                 nullptr, nullptr, nullptr, nullptr, n);
    gemm_k<128, false><<<gGemm, TB, 0, stream>>>(B2, Wr, B1, nullptr, bs, 1, 1,
                                                 nullptr, nullptr, nullptr, nullptr, n);

    // ---- Layer 3: GAT(1 head) + ReLU -> B2 (attn dots fused into GEMM)
    gemm_k<128, true><<<gGemm, TB, 0, stream>>>(B1, Wg, B0, M16a, nullptr, 0, 0,
                                                a_s, a_d, as_, ad_, n);
    attn_reduce_k<<<gQuad, TB, 0, stream>>>(rowptr, srcs, as_, ad_, recG, den_, n);
    gatherbf_k<128, 2><<<gGa128, TB, 0, stream>>>(M16a, B0, B2, nullptr, rowptr, srcs, recG,
                                                  nullptr, den_, bg, n);

    // ---- Output layer: GCN(128->64), no ReLU -> d_out
    gemm_k<64, false><<<gGemm, TB, 0, stream>>>(B2, Wo, B1, M16a, nullptr, 0, 0,
                                                nullptr, nullptr, nullptr, nullptr, n);
    gatherbf_k<64, 3><<<gGa64, TB, 0, stream>>>(M16a, B1, (float*)d_out, nullptr, rowptr, srcs, recA,
                                                dinv, nullptr, bo, n);
}

// Round 8
// 516.654 us; speedup vs baseline: 1.1399x; 1.1399x over previous
//
#include <hip/hip_runtime.h>
#include <math.h>

// ---------------------------------------------------------------------------
// DynamicGNN: GCN -> SAGE(mean) -> GAT(1 head) -> GCN(128->64)
// N=50000, E=1.6M, D=128, OUT=64, fp32 compute.
// v8: GEMM A-tile staged in LDS (kills 32-way redundant broadcast VMEM loads
//     that made each GEMM ~50us); SAGE's two GEMMs fused into one K=256 pass.
//     Gathers/CSR unchanged from v7.
// ---------------------------------------------------------------------------

#define BUCKET_BITS 8
#define BUCKET_SZ   256
#define NBMAX       256

__device__ __forceinline__ float leaky02(float x) { return x > 0.0f ? x : 0.2f * x; }
__device__ __forceinline__ float bflo(unsigned u) { return __uint_as_float(u << 16); }
__device__ __forceinline__ float bfhi(unsigned u) { return __uint_as_float(u & 0xFFFF0000u); }
__device__ __forceinline__ unsigned short f2bf(float f) {
    unsigned u = __float_as_uint(f);
    u += 0x7FFFu + ((u >> 16) & 1u);   // round-to-nearest-even
    return (unsigned short)(u >> 16);
}

// ---------------- GEMM: C[n x NO] = A@W (+ A1@W1 if DUAL) + bias, relu
// A-tile (32 rows x 32 k) and W-tile (32 k x NO) staged in LDS per k-tile.
// As stride 36 floats: staging writes land in distinct banks per row-group.
// DOTS: emit as_[r] = row.a_s, ad_[r] = row.a_d (GAT) from the fp32 result.
template<int NO, bool DOTS, bool DUAL>
__global__ __launch_bounds__(256) void gemm_k(
    const float* __restrict__ A, const float* __restrict__ W,
    const float* __restrict__ A1, const float* __restrict__ W1,
    float* __restrict__ C, unsigned short* __restrict__ C16,
    const float* __restrict__ bias, int relu,
    const float* __restrict__ a_s, const float* __restrict__ a_d,
    float* __restrict__ as_, float* __restrict__ ad_, int n)
{
    constexpr int CHUNK = NO / 32;
    __shared__ float Ws[32 * NO];
    __shared__ float As[32 * 36];
    const int tid = threadIdx.x;
    const int row0 = blockIdx.x * 32;
    const int rb = ((tid >> 5) & 7) * 4;   // 4 rows per thread
    const int cb = tid & 31;               // col lane -> cols [cb*CHUNK, +CHUNK)

    int gr[4];
    bool valid[4];
#pragma unroll
    for (int i = 0; i < 4; i++) {
        int r = row0 + rb + i;
        valid[i] = (r < n);
        gr[i] = valid[i] ? r : (n - 1);
    }
    // staging coords: thread -> (row, k4)
    const int srow = tid >> 3;
    const int sk4 = tid & 7;
    int sr = row0 + srow; if (sr >= n) sr = n - 1;

    float acc[4][CHUNK];
#pragma unroll
    for (int i = 0; i < 4; i++)
#pragma unroll
        for (int c = 0; c < CHUNK; c++) acc[i][c] = 0.0f;

    const int ntiles = DUAL ? 8 : 4;
    for (int t = 0; t < ntiles; t++) {
        const float* Asrc = (DUAL && t >= 4) ? A1 : A;
        const float* Wsrc = (DUAL && t >= 4) ? W1 : W;
        const int tt = (DUAL && t >= 4) ? (t - 4) : t;
        __syncthreads();
        const float4* Wt = (const float4*)(Wsrc + tt * 32 * NO);
        for (int i = tid; i < 32 * NO / 4; i += 256) ((float4*)Ws)[i] = Wt[i];
        *(float4*)&As[srow * 36 + sk4 * 4] =
            ((const float4*)Asrc)[(size_t)sr * 32 + tt * 8 + sk4];
        __syncthreads();
#pragma unroll
        for (int k4 = 0; k4 < 8; k4++) {
            float4 a4[4];
#pragma unroll
            for (int i = 0; i < 4; i++)
                a4[i] = *(const float4*)&As[(rb + i) * 36 + k4 * 4];
#pragma unroll
            for (int kk = 0; kk < 4; kk++) {
                const int koff = k4 * 4 + kk;
                float wv[CHUNK];
#pragma unroll
                for (int c = 0; c < CHUNK; c++) wv[c] = Ws[koff * NO + cb * CHUNK + c];
                const float av[4] = {
                    kk == 0 ? a4[0].x : kk == 1 ? a4[0].y : kk == 2 ? a4[0].z : a4[0].w,
                    kk == 0 ? a4[1].x : kk == 1 ? a4[1].y : kk == 2 ? a4[1].z : a4[1].w,
                    kk == 0 ? a4[2].x : kk == 1 ? a4[2].y : kk == 2 ? a4[2].z : a4[2].w,
                    kk == 0 ? a4[3].x : kk == 1 ? a4[3].y : kk == 2 ? a4[3].z : a4[3].w };
#pragma unroll
                for (int i = 0; i < 4; i++)
#pragma unroll
                    for (int c = 0; c < CHUNK; c++)
                        acc[i][c] = fmaf(av[i], wv[c], acc[i][c]);
            }
        }
    }

    if (DOTS) {
        float asv[CHUNK], adv[CHUNK];
#pragma unroll
        for (int c = 0; c < CHUNK; c++) { asv[c] = a_s[cb * CHUNK + c]; adv[c] = a_d[cb * CHUNK + c]; }
#pragma unroll
        for (int i = 0; i < 4; i++) {
            float ps = 0.f, pd = 0.f;
#pragma unroll
            for (int c = 0; c < CHUNK; c++) {
                ps = fmaf(acc[i][c], asv[c], ps);
                pd = fmaf(acc[i][c], adv[c], pd);
            }
#pragma unroll
            for (int off = 16; off > 0; off >>= 1) {
                ps += __shfl_xor(ps, off);
                pd += __shfl_xor(pd, off);
            }
            if (cb == 0 && valid[i]) { as_[gr[i]] = ps; ad_[gr[i]] = pd; }
        }
    }

#pragma unroll
    for (int i = 0; i < 4; i++) {
        if (valid[i]) {
            const size_t base = (size_t)gr[i] * NO + cb * CHUNK;
            float vv[CHUNK];
#pragma unroll
            for (int c = 0; c < CHUNK; c++) {
                float v = acc[i][c];
                if (bias) v += bias[cb * CHUNK + c];
                if (relu) v = fmaxf(v, 0.0f);
                vv[c] = v;
            }
            if constexpr (CHUNK == 4) {
                float4 p; p.x = vv[0]; p.y = vv[1]; p.z = vv[2]; p.w = vv[3];
                *(float4*)(C + base) = p;
            } else {
                float2 p; p.x = vv[0]; p.y = vv[1];
                *(float2*)(C + base) = p;
            }
            if (C16) {
                if constexpr (CHUNK == 4) {
                    ushort4 q; q.x = f2bf(vv[0]); q.y = f2bf(vv[1]); q.z = f2bf(vv[2]); q.w = f2bf(vv[3]);
                    *(ushort4*)(C16 + base) = q;
                } else {
                    ushort2 q; q.x = f2bf(vv[0]); q.y = f2bf(vv[1]);
                    *(ushort2*)(C16 + base) = q;
                }
            }
        }
    }
}

// ---------------- CSR build (atomic-free on global data) ----------------
#define BH_CH 4096
__global__ __launch_bounds__(256) void bhist_k(const int* __restrict__ dst,
                                               int* __restrict__ btot, int nE) {
    __shared__ int lh[NBMAX];
    const int t = threadIdx.x;
    lh[t] = 0;
    __syncthreads();
    const int base = blockIdx.x * BH_CH;
#pragma unroll
    for (int j = 0; j < BH_CH / 256; j++) {
        int e = base + j * 256 + t;
        if (e < nE) atomicAdd(&lh[dst[e] >> BUCKET_BITS], 1);
    }
    __syncthreads();
    if (lh[t]) atomicAdd(&btot[t], lh[t]);
}

__global__ __launch_bounds__(256) void bscan_k(const int* __restrict__ btot,
                                               int* __restrict__ bofs,
                                               int* __restrict__ bcur, int nb) {
    __shared__ int sm[256];
    const int t = threadIdx.x;
    int v = (t < nb) ? btot[t] : 0;
    sm[t] = v;
    __syncthreads();
    for (int off = 1; off < 256; off <<= 1) {
        int tv = (t >= off) ? sm[t - off] : 0;
        __syncthreads();
        sm[t] += tv;
        __syncthreads();
    }
    if (t < nb) {
        int excl = sm[t] - v;
        bofs[t] = excl;
        bcur[t] = excl;
        if (t == nb - 1) bofs[nb] = sm[t];
    }
}

#define PART_CH 4096
__global__ __launch_bounds__(256) void part_k(
    const int* __restrict__ src, const int* __restrict__ dst,
    int* __restrict__ bcur, unsigned long long* __restrict__ part, int nE)
{
    __shared__ int cnt[NBMAX];
    __shared__ int cur[NBMAX];
    const int base = blockIdx.x * PART_CH;
    const int t = threadIdx.x;
    cnt[t] = 0;
    __syncthreads();
    int d[PART_CH / 256], s[PART_CH / 256];
#pragma unroll
    for (int j = 0; j < PART_CH / 256; j++) {
        int e = base + j * 256 + t;
        if (e < nE) {
            d[j] = dst[e]; s[j] = src[e];
            atomicAdd(&cnt[d[j] >> BUCKET_BITS], 1);
        } else d[j] = -1;
    }
    __syncthreads();
    {
        int c = cnt[t];
        cur[t] = c ? atomicAdd(&bcur[t], c) : 0;
    }
    __syncthreads();
#pragma unroll
    for (int j = 0; j < PART_CH / 256; j++) {
        if (d[j] >= 0) {
            int p = atomicAdd(&cur[d[j] >> BUCKET_BITS], 1);
            part[p] = ((unsigned long long)(unsigned)d[j] << 32) | (unsigned)s[j];
        }
    }
}

__global__ __launch_bounds__(256) void csr_k(
    const unsigned long long* __restrict__ part, const int* __restrict__ bofs,
    int* __restrict__ rowptr, int* __restrict__ srcs,
    float* __restrict__ dinv, float* __restrict__ invm, int n, int nE)
{
    __shared__ int lcnt[BUCKET_SZ];
    __shared__ int sm[BUCKET_SZ];
    __shared__ int lcur[BUCKET_SZ];
    const int b = blockIdx.x;
    const int t = threadIdx.x;
    const int base = bofs[b];
    const int cntE = bofs[b + 1] - base;

    lcnt[t] = 0;
    __syncthreads();
#pragma unroll 4
    for (int e = t; e < cntE; e += 256) {
        int dl = (int)(part[base + e] >> 32) & (BUCKET_SZ - 1);
        atomicAdd(&lcnt[dl], 1);
    }
    __syncthreads();
    int v = lcnt[t];
    sm[t] = v;
    __syncthreads();
    for (int off = 1; off < 256; off <<= 1) {
        int tv = (t >= off) ? sm[t - off] : 0;
        __syncthreads();
        sm[t] += tv;
        __syncthreads();
    }
    const int excl = sm[t] - v;
    const int node = (b << BUCKET_BITS) + t;
    if (node < n) {
        rowptr[node] = base + excl;
        float dg = (float)v;
        dinv[node] = rsqrtf(dg + 1.0f);
        invm[node] = 1.0f / fmaxf(dg, 1.0f);
        if (node == n - 1) rowptr[n] = nE;
    }
    lcur[t] = excl;
    __syncthreads();
#pragma unroll 4
    for (int e = t; e < cntE; e += 256) {
        unsigned long long w = part[base + e];
        int dl = (int)(w >> 32) & (BUCKET_SZ - 1);
        int pos = atomicAdd(&lcur[dl], 1);
        srcs[base + pos] = (int)(unsigned)w;
    }
}

// build GCN edge records: recA[e] = (src, dinv[src])
__global__ void wfill_k(const int* __restrict__ srcs, const float* __restrict__ dinv,
                        uint2* __restrict__ recA, int nE) {
    int e = blockIdx.x * blockDim.x + threadIdx.x;
    if (e < nE) {
        int s = srcs[e];
        recA[e] = make_uint2((unsigned)s, __float_as_uint(dinv[s]));
    }
}

// ---------------- record-based bf16 gather ----------------
// MODE 0: SAGE mean (srcs only, w=1, scale by invm). MODE 1: GCN + bias + ReLU
// (recA weights, end-scale by dinv_d; +bf16 mirror). MODE 2: GAT + bias + ReLU
// (recG alpha weights, self-alpha in den_). MODE 3: GCN out, no ReLU.
template<int F, int MODE>
__global__ __launch_bounds__(256) void gatherbf_k(
    const unsigned short* __restrict__ H16, const float* __restrict__ Hf,
    float* __restrict__ out, unsigned short* __restrict__ out16,
    const int* __restrict__ rowptr, const int* __restrict__ srcs,
    const uint2* __restrict__ REC, const float* __restrict__ dinv,
    const float* __restrict__ den_, const float* __restrict__ bias, int n)
{
    constexpr int LPN = F / 4;
    constexpr int NPB = 256 / LPN;
    const int node = blockIdx.x * NPB + (int)(threadIdx.x / LPN);
    const int lane = (int)(threadIdx.x & (LPN - 1));
    if (node >= n) return;
    const int beg = rowptr[node], end = rowptr[node + 1];

    const uint2* __restrict__ H2 = (const uint2*)H16;
    float4 acc = make_float4(0.f, 0.f, 0.f, 0.f);

    int k = beg;
    for (; k + 8 <= end; k += 8) {
        unsigned sidx[8]; float wv[8];
        if (MODE == 0) {
#pragma unroll
            for (int j = 0; j < 8; j++) { sidx[j] = (unsigned)srcs[k + j]; wv[j] = 1.0f; }
        } else {
#pragma unroll
            for (int j = 0; j < 8; j++) {
                uint2 rc = REC[k + j];
                sidx[j] = rc.x; wv[j] = __uint_as_float(rc.y);
            }
        }
        uint2 h[8];
#pragma unroll
        for (int j = 0; j < 8; j++) h[j] = H2[(size_t)sidx[j] * LPN + lane];
#pragma unroll
        for (int j = 0; j < 8; j++) {
            if (MODE == 0) {
                acc.x += bflo(h[j].x); acc.y += bfhi(h[j].x);
                acc.z += bflo(h[j].y); acc.w += bfhi(h[j].y);
            } else {
                acc.x = fmaf(wv[j], bflo(h[j].x), acc.x);
                acc.y = fmaf(wv[j], bfhi(h[j].x), acc.y);
                acc.z = fmaf(wv[j], bflo(h[j].y), acc.z);
                acc.w = fmaf(wv[j], bfhi(h[j].y), acc.w);
            }
        }
    }
    if (k < end) {
        unsigned sidx[8]; float wv[8]; bool act[8];
#pragma unroll
        for (int j = 0; j < 8; j++) {
            int kk = k + j;
            act[j] = (kk < end);
            int idx = act[j] ? kk : (end - 1);
            if (MODE == 0) { sidx[j] = (unsigned)srcs[idx]; wv[j] = act[j] ? 1.0f : 0.0f; }
            else {
                uint2 rc = REC[idx];
                sidx[j] = rc.x; wv[j] = act[j] ? __uint_as_float(rc.y) : 0.0f;
            }
        }
        uint2 h[8];
#pragma unroll
        for (int j = 0; j < 8; j++) h[j] = H2[(size_t)sidx[j] * LPN + lane];
#pragma unroll
        for (int j = 0; j < 8; j++) {
            acc.x = fmaf(wv[j], bflo(h[j].x), acc.x);
            acc.y = fmaf(wv[j], bfhi(h[j].x), acc.y);
            acc.z = fmaf(wv[j], bflo(h[j].y), acc.z);
            acc.w = fmaf(wv[j], bfhi(h[j].y), acc.w);
        }
    }

    const size_t oi = (size_t)node * LPN + lane;
    float4 r = acc;
    if (MODE == 0) {
        float sc = dinv[node];            // invm passed via dinv arg
        r.x *= sc; r.y *= sc; r.z *= sc; r.w *= sc;
    } else {
        float4 self = ((const float4*)Hf)[oi];
        float4 bv = ((const float4*)bias)[lane];
        float sw, os;
        if (MODE == 2) { sw = den_[node]; os = 1.0f; }            // self-alpha
        else { float dv = dinv[node]; sw = dv * dv; os = dv; }    // GCN factorized
        r.x = os * r.x + sw * self.x + bv.x;
        r.y = os * r.y + sw * self.y + bv.y;
        r.z = os * r.z + sw * self.z + bv.z;
        r.w = os * r.w + sw * self.w + bv.w;
        if (MODE != 3) {
            r.x = fmaxf(r.x, 0.f); r.y = fmaxf(r.y, 0.f);
            r.z = fmaxf(r.z, 0.f); r.w = fmaxf(r.w, 0.f);
        }
    }
    ((float4*)out)[oi] = r;
    if (MODE == 1) {
        ushort4 q; q.x = f2bf(r.x); q.y = f2bf(r.y); q.z = f2bf(r.z); q.w = f2bf(r.w);
        ((ushort4*)out16)[oi] = q;
    }
}

// ---------------- GAT softmax: recG[e]=(src,alpha), den_[node]=self-alpha ----
__global__ __launch_bounds__(256) void attn_reduce_k(
    const int* __restrict__ rowptr, const int* __restrict__ srcs,
    const float* __restrict__ as_, const float* __restrict__ ad_,
    uint2* __restrict__ recG, float* __restrict__ den_, int n)
{
    int node = blockIdx.x * 4 + (int)(threadIdx.x >> 6);
    int lane = threadIdx.x & 63;
    if (node >= n) return;
    int beg = rowptr[node], end = rowptr[node + 1];
    float ad_d = ad_[node];
    float self_e = leaky02(as_[node] + ad_d);
    float mx = self_e;
    for (int k = beg + lane; k < end; k += 64)
        mx = fmaxf(mx, leaky02(as_[srcs[k]] + ad_d));
    for (int off = 32; off > 0; off >>= 1) mx = fmaxf(mx, __shfl_xor(mx, off, 64));
    float sum = (lane == 0) ? expf(self_e - mx) : 0.0f;
    for (int k = beg + lane; k < end; k += 64)
        sum += expf(leaky02(as_[srcs[k]] + ad_d) - mx);
    for (int off = 32; off > 0; off >>= 1) sum += __shfl_xor(sum, off, 64);
    float rden = 1.0f / sum;
    for (int k = beg + lane; k < end; k += 64) {
        int s = srcs[k];
        float a = expf(leaky02(as_[s] + ad_d) - mx) * rden;
        recG[k] = make_uint2((unsigned)s, __float_as_uint(a));
    }
    if (lane == 0) den_[node] = expf(self_e - mx) * rden;
}

// ---------------------------------------------------------------------------
extern "C" void kernel_launch(void* const* d_in, const int* in_sizes, int n_in,
                              void* d_out, int out_size, void* d_ws, size_t ws_size,
                              hipStream_t stream)
{
    const float* x   = (const float*)d_in[0];
    const int*   ei  = (const int*)d_in[1];
    const float* W1  = (const float*)d_in[2];
    const float* b1  = (const float*)d_in[3];
    const float* Wl  = (const float*)d_in[4];
    const float* Wr  = (const float*)d_in[5];
    const float* bs  = (const float*)d_in[6];
    const float* Wg  = (const float*)d_in[7];
    const float* a_s = (const float*)d_in[8];
    const float* a_d = (const float*)d_in[9];
    const float* bg  = (const float*)d_in[10];
    const float* Wo  = (const float*)d_in[11];
    const float* bo  = (const float*)d_in[12];

    const int n  = in_sizes[0] / 128;
    const int nE = in_sizes[1] / 2;
    const int* src = ei;
    const int* dst = ei + nE;

    char* w = (char*)d_ws;
    auto alloc = [&](size_t bytes) { char* p = w; w += (bytes + 255) & ~(size_t)255; return p; };
    float* B0     = (float*)alloc((size_t)n * 128 * 4);
    float* B1     = (float*)alloc((size_t)n * 128 * 4);   // also CSR partition scratch
    float* B2     = (float*)alloc((size_t)n * 128 * 4);
    unsigned short* M16a = (unsigned short*)alloc((size_t)n * 128 * 2);
    unsigned short* M16b = (unsigned short*)alloc((size_t)n * 128 * 2);
    int*   srcs   = (int*)alloc((size_t)nE * 4);
    uint2* recA   = (uint2*)alloc((size_t)nE * 8);
    uint2* recG   = (uint2*)alloc((size_t)nE * 8);
    int*   rowptr = (int*)alloc((size_t)(n + 1) * 4);
    int*   btot   = (int*)alloc(NBMAX * 4);
    int*   bofs   = (int*)alloc((NBMAX + 1) * 4);
    int*   bcur   = (int*)alloc(NBMAX * 4);
    float* dinv   = (float*)alloc((size_t)n * 4);
    float* invm   = (float*)alloc((size_t)n * 4);
    float* as_    = (float*)alloc((size_t)n * 4);
    float* ad_    = (float*)alloc((size_t)n * 4);
    float* den_   = (float*)alloc((size_t)n * 4);
    unsigned long long* part = (unsigned long long*)B1;

    const int TB = 256;
    auto cdiv = [](long long a, long long b) { return (int)((a + b - 1) / b); };
    const int nb     = cdiv(n, BUCKET_SZ);
    const int gBh    = cdiv(nE, BH_CH);
    const int gPart  = cdiv(nE, PART_CH);
    const int gE     = cdiv(nE, TB);
    const int gGemm  = cdiv(n, 32);
    const int gGa128 = cdiv(n, 8);
    const int gGa64  = cdiv(n, 16);
    const int gQuad  = cdiv(n, 4);

    // ---- CSR build: bucket hist -> scan -> partition -> per-bucket LDS CSR
    hipMemsetAsync(btot, 0, NBMAX * 4, stream);
    bhist_k<<<gBh, TB, 0, stream>>>(dst, btot, nE);
    bscan_k<<<1, 256, 0, stream>>>(btot, bofs, bcur, nb);
    part_k<<<gPart, TB, 0, stream>>>(src, dst, bcur, part, nE);
    csr_k<<<nb, TB, 0, stream>>>(part, bofs, rowptr, srcs, dinv, invm, n, nE);
    wfill_k<<<gE, TB, 0, stream>>>(srcs, dinv, recA, nE);

    // ---- Layer 1: GCN(128->128) + ReLU -> B2 (+M16b)
    gemm_k<128, false, false><<<gGemm, TB, 0, stream>>>(
        x, W1, nullptr, nullptr, B0, M16a, nullptr, 0,
        nullptr, nullptr, nullptr, nullptr, n);
    gatherbf_k<128, 1><<<gGa128, TB, 0, stream>>>(M16a, B0, B2, M16b, rowptr, srcs, recA,
                                                  dinv, nullptr, b1, n);

    // ---- Layer 2: SAGE(mean) + ReLU -> B1 (fused dual GEMM: mean@Wl + h1@Wr)
    gatherbf_k<128, 0><<<gGa128, TB, 0, stream>>>(M16b, nullptr, B0, nullptr, rowptr, srcs, nullptr,
                                                  invm, nullptr, nullptr, n);
    gemm_k<128, false, true><<<gGemm, TB, 0, stream>>>(
        B0, Wl, B2, Wr, B1, nullptr, bs, 1,
        nullptr, nullptr, nullptr, nullptr, n);

    // ---- Layer 3: GAT(1 head) + ReLU -> B2 (attn dots fused into GEMM)
    gemm_k<128, true, false><<<gGemm, TB, 0, stream>>>(
        B1, Wg, nullptr, nullptr, B0, M16a, nullptr, 0,
        a_s, a_d, as_, ad_, n);
    attn_reduce_k<<<gQuad, TB, 0, stream>>>(rowptr, srcs, as_, ad_, recG, den_, n);
    gatherbf_k<128, 2><<<gGa128, TB, 0, stream>>>(M16a, B0, B2, nullptr, rowptr, srcs, recG,
                                                  nullptr, den_, bg, n);

    // ---- Output layer: GCN(128->64), no ReLU -> d_out
    gemm_k<64, false, false><<<gGemm, TB, 0, stream>>>(
        B2, Wo, nullptr, nullptr, B1, M16a, nullptr, 0,
        nullptr, nullptr, nullptr, nullptr, n);
    gatherbf_k<64, 3><<<gGa64, TB, 0, stream>>>(M16a, B1, (float*)d_out, nullptr, rowptr, srcs, recA,
                                                dinv, nullptr, bo, n);
}

// Round 9
// 410.699 us; speedup vs baseline: 1.4340x; 1.2580x over previous
//
#include <hip/hip_runtime.h>
#include <math.h>

// ---------------------------------------------------------------------------
// DynamicGNN: GCN -> SAGE(mean) -> GAT(1 head) -> GCN(128->64)
// N=50000, E=1.6M, D=128, OUT=64.
// v9: bf16 MFMA GEMMs (16x16x32), bf16-only feature chain (no fp32 feature
//     buffers), GCN mirrors pre-scaled by dinv (recA/wfill deleted), GAT dots
//     as a small bf16 pass. Gathers keep v8 structure, bf16 in/out.
// ---------------------------------------------------------------------------

#define BUCKET_BITS 8
#define BUCKET_SZ   256
#define NBMAX       256

typedef short short8 __attribute__((ext_vector_type(8)));
typedef float f32x4 __attribute__((ext_vector_type(4)));

__device__ __forceinline__ float leaky02(float x) { return x > 0.0f ? x : 0.2f * x; }
__device__ __forceinline__ float bflo(unsigned u) { return __uint_as_float(u << 16); }
__device__ __forceinline__ float bfhi(unsigned u) { return __uint_as_float(u & 0xFFFF0000u); }
__device__ __forceinline__ unsigned short f2bf(float f) {
    unsigned u = __float_as_uint(f);
    u += 0x7FFFu + ((u >> 16) & 1u);   // round-to-nearest-even
    return (unsigned short)(u >> 16);
}

// ---------------- MFMA GEMM: C16[n x NO] = bf16( scale? * (A@W (+A1@W1)) +bias )
// A: bf16 row-major [n x 128] (or fp32 if AFP32). W fp32 [128 x NO] packed to
// bf16 MFMA B-fragments in LDS. 256 thr = 4 waves; block = 64 rows; wave = 16
// rows x NO cols (CT col-tiles of 16). mfma_f32_16x16x32_bf16:
//   A-frag: lane(m=lane&15, q=lane>>4) holds k = q*8+j  (j=0..7)
//   B-frag: lane(n=lane&15, q)          holds k = q*8+j
//   D:      col = lane&15, row = q*4 + reg
template<int NO, bool AFP32, bool SCALE, bool BIASRELU, bool DUAL>
__global__ __launch_bounds__(256) void mgemm_k(
    const void* __restrict__ Av, const float* __restrict__ W,
    const void* __restrict__ A1v, const float* __restrict__ W1,
    unsigned short* __restrict__ C16,
    const float* __restrict__ scale, const float* __restrict__ bias, int n)
{
    constexpr int CT = NO / 16;
    constexpr int LCT = (CT == 8) ? 3 : 2;
    __shared__ unsigned short Wp[128 * NO];   // packed B-frags (32/16 KB)
    const int tid = threadIdx.x;
    const int wave = tid >> 6, lane = tid & 63;
    const int q = lane >> 4, ml = lane & 15;
    const int row0 = blockIdx.x * 64 + wave * 16;
    int arow = row0 + ml; if (arow >= n) arow = n - 1;

    f32x4 acc[CT];
#pragma unroll
    for (int c = 0; c < CT; c++) acc[c] = {0.f, 0.f, 0.f, 0.f};

    for (int half = 0; half < (DUAL ? 2 : 1); half++) {
        const float* Wsrc = half ? W1 : W;
        const void* Asrc = half ? A1v : Av;
        __syncthreads();
        // stage W as packed fragments: frag f -> 8 bf16 of column nn, k=kbase..+7
        for (int f = tid; f < 16 * NO; f += 256) {
            int nl = f & 15, qq = (f >> 4) & 3, c = (f >> 6) & (CT - 1), kb = f >> (6 + LCT);
            int kbase = kb * 32 + qq * 8, nn = c * 16 + nl;
            unsigned r[4];
#pragma unroll
            for (int p = 0; p < 4; p++) {
                unsigned lo = f2bf(Wsrc[(size_t)(kbase + 2 * p) * NO + nn]);
                unsigned hi = f2bf(Wsrc[(size_t)(kbase + 2 * p + 1) * NO + nn]);
                r[p] = lo | (hi << 16);
            }
            *(uint4*)(Wp + (size_t)f * 8) = make_uint4(r[0], r[1], r[2], r[3]);
        }
        __syncthreads();
#pragma unroll
        for (int kb = 0; kb < 4; kb++) {
            short8 afr;
            if (AFP32) {
                const float* Af = (const float*)Asrc + (size_t)arow * 128 + kb * 32 + q * 8;
#pragma unroll
                for (int j = 0; j < 8; j++) afr[j] = (short)f2bf(Af[j]);
            } else {
                afr = *(const short8*)((const unsigned short*)Asrc +
                                       (size_t)arow * 128 + kb * 32 + q * 8);
            }
#pragma unroll
            for (int c = 0; c < CT; c++) {
                short8 bfr = *(const short8*)(Wp + ((size_t)(kb * CT + c) * 64 + lane) * 8);
                acc[c] = __builtin_amdgcn_mfma_f32_16x16x32_bf16(afr, bfr, acc[c], 0, 0, 0);
            }
        }
    }

    float sc[4];
    if (SCALE) {
#pragma unroll
        for (int r = 0; r < 4; r++) {
            int row = row0 + q * 4 + r;
            sc[r] = scale[row < n ? row : 0];
        }
    }
#pragma unroll
    for (int c = 0; c < CT; c++) {
        float bv = BIASRELU ? bias[c * 16 + ml] : 0.0f;
#pragma unroll
        for (int r = 0; r < 4; r++) {
            int row = row0 + q * 4 + r;
            if (row < n) {
                float v = acc[c][r];
                if (SCALE) v *= sc[r];
                if (BIASRELU) v = fmaxf(v + bv, 0.0f);
                C16[(size_t)row * NO + c * 16 + ml] = f2bf(v);
            }
        }
    }
}

// ---------------- CSR build (atomic-free on global data) ----------------
#define BH_CH 4096
__global__ __launch_bounds__(256) void bhist_k(const int* __restrict__ dst,
                                               int* __restrict__ btot, int nE) {
    __shared__ int lh[NBMAX];
    const int t = threadIdx.x;
    lh[t] = 0;
    __syncthreads();
    const int base = blockIdx.x * BH_CH;
#pragma unroll
    for (int j = 0; j < BH_CH / 256; j++) {
        int e = base + j * 256 + t;
        if (e < nE) atomicAdd(&lh[dst[e] >> BUCKET_BITS], 1);
    }
    __syncthreads();
    if (lh[t]) atomicAdd(&btot[t], lh[t]);
}

__global__ __launch_bounds__(256) void bscan_k(const int* __restrict__ btot,
                                               int* __restrict__ bofs,
                                               int* __restrict__ bcur, int nb) {
    __shared__ int sm[256];
    const int t = threadIdx.x;
    int v = (t < nb) ? btot[t] : 0;
    sm[t] = v;
    __syncthreads();
    for (int off = 1; off < 256; off <<= 1) {
        int tv = (t >= off) ? sm[t - off] : 0;
        __syncthreads();
        sm[t] += tv;
        __syncthreads();
    }
    if (t < nb) {
        int excl = sm[t] - v;
        bofs[t] = excl;
        bcur[t] = excl;
        if (t == nb - 1) bofs[nb] = sm[t];
    }
}

#define PART_CH 4096
__global__ __launch_bounds__(256) void part_k(
    const int* __restrict__ src, const int* __restrict__ dst,
    int* __restrict__ bcur, unsigned long long* __restrict__ part, int nE)
{
    __shared__ int cnt[NBMAX];
    __shared__ int cur[NBMAX];
    const int base = blockIdx.x * PART_CH;
    const int t = threadIdx.x;
    cnt[t] = 0;
    __syncthreads();
    int d[PART_CH / 256], s[PART_CH / 256];
#pragma unroll
    for (int j = 0; j < PART_CH / 256; j++) {
        int e = base + j * 256 + t;
        if (e < nE) {
            d[j] = dst[e]; s[j] = src[e];
            atomicAdd(&cnt[d[j] >> BUCKET_BITS], 1);
        } else d[j] = -1;
    }
    __syncthreads();
    {
        int c = cnt[t];
        cur[t] = c ? atomicAdd(&bcur[t], c) : 0;
    }
    __syncthreads();
#pragma unroll
    for (int j = 0; j < PART_CH / 256; j++) {
        if (d[j] >= 0) {
            int p = atomicAdd(&cur[d[j] >> BUCKET_BITS], 1);
            part[p] = ((unsigned long long)(unsigned)d[j] << 32) | (unsigned)s[j];
        }
    }
}

__global__ __launch_bounds__(256) void csr_k(
    const unsigned long long* __restrict__ part, const int* __restrict__ bofs,
    int* __restrict__ rowptr, int* __restrict__ srcs,
    float* __restrict__ dinv, float* __restrict__ invm, int n, int nE)
{
    __shared__ int lcnt[BUCKET_SZ];
    __shared__ int sm[BUCKET_SZ];
    __shared__ int lcur[BUCKET_SZ];
    const int b = blockIdx.x;
    const int t = threadIdx.x;
    const int base = bofs[b];
    const int cntE = bofs[b + 1] - base;

    lcnt[t] = 0;
    __syncthreads();
#pragma unroll 4
    for (int e = t; e < cntE; e += 256) {
        int dl = (int)(part[base + e] >> 32) & (BUCKET_SZ - 1);
        atomicAdd(&lcnt[dl], 1);
    }
    __syncthreads();
    int v = lcnt[t];
    sm[t] = v;
    __syncthreads();
    for (int off = 1; off < 256; off <<= 1) {
        int tv = (t >= off) ? sm[t - off] : 0;
        __syncthreads();
        sm[t] += tv;
        __syncthreads();
    }
    const int excl = sm[t] - v;
    const int node = (b << BUCKET_BITS) + t;
    if (node < n) {
        rowptr[node] = base + excl;
        float dg = (float)v;
        dinv[node] = rsqrtf(dg + 1.0f);
        invm[node] = 1.0f / fmaxf(dg, 1.0f);
        if (node == n - 1) rowptr[n] = nE;
    }
    lcur[t] = excl;
    __syncthreads();
#pragma unroll 4
    for (int e = t; e < cntE; e += 256) {
        unsigned long long w = part[base + e];
        int dl = (int)(w >> 32) & (BUCKET_SZ - 1);
        int pos = atomicAdd(&lcur[dl], 1);
        srcs[base + pos] = (int)(unsigned)w;
    }
}

// ---------------- bf16 gather ----------------
// MODE 0: SAGE mean = invm * sum(H[s]); emit bf16.
// MODE 1: GCN: dinv_d * (sum + self) + bias, relu; emit bf16. (H pre-scaled by dinv)
// MODE 2: GAT: sum(alpha*H[s]) + den_*self + bias, relu; emit bf16. (REC = (src,alpha))
// MODE 3: GCN out: dinv_d * (sum + self) + bias; fp32 out.
template<int F, int MODE>
__global__ __launch_bounds__(256) void gatherbf_k(
    const unsigned short* __restrict__ H16, float* __restrict__ outf,
    unsigned short* __restrict__ out16,
    const int* __restrict__ rowptr, const int* __restrict__ srcs,
    const uint2* __restrict__ REC, const float* __restrict__ dinv,
    const float* __restrict__ den_, const float* __restrict__ bias, int n)
{
    constexpr int LPN = F / 4;
    constexpr int NPB = 256 / LPN;
    const int node = blockIdx.x * NPB + (int)(threadIdx.x / LPN);
    const int lane = (int)(threadIdx.x & (LPN - 1));
    if (node >= n) return;
    const int beg = rowptr[node], end = rowptr[node + 1];

    const uint2* __restrict__ H2 = (const uint2*)H16;
    float4 acc = make_float4(0.f, 0.f, 0.f, 0.f);

    int k = beg;
    for (; k + 8 <= end; k += 8) {
        unsigned sidx[8]; float wv[8];
        if (MODE == 2) {
#pragma unroll
            for (int j = 0; j < 8; j++) {
                uint2 rc = REC[k + j];
                sidx[j] = rc.x; wv[j] = __uint_as_float(rc.y);
            }
        } else {
#pragma unroll
            for (int j = 0; j < 8; j++) { sidx[j] = (unsigned)srcs[k + j]; wv[j] = 1.0f; }
        }
        uint2 h[8];
#pragma unroll
        for (int j = 0; j < 8; j++) h[j] = H2[(size_t)sidx[j] * LPN + lane];
#pragma unroll
        for (int j = 0; j < 8; j++) {
            if (MODE == 2) {
                acc.x = fmaf(wv[j], bflo(h[j].x), acc.x);
                acc.y = fmaf(wv[j], bfhi(h[j].x), acc.y);
                acc.z = fmaf(wv[j], bflo(h[j].y), acc.z);
                acc.w = fmaf(wv[j], bfhi(h[j].y), acc.w);
            } else {
                acc.x += bflo(h[j].x); acc.y += bfhi(h[j].x);
                acc.z += bflo(h[j].y); acc.w += bfhi(h[j].y);
            }
        }
    }
    if (k < end) {
        unsigned sidx[8]; float wv[8]; bool act[8];
#pragma unroll
        for (int j = 0; j < 8; j++) {
            int kk = k + j;
            act[j] = (kk < end);
            int idx = act[j] ? kk : (end - 1);
            if (MODE == 2) {
                uint2 rc = REC[idx];
                sidx[j] = rc.x; wv[j] = act[j] ? __uint_as_float(rc.y) : 0.0f;
            } else {
                sidx[j] = (unsigned)srcs[idx]; wv[j] = act[j] ? 1.0f : 0.0f;
            }
        }
        uint2 h[8];
#pragma unroll
        for (int j = 0; j < 8; j++) h[j] = H2[(size_t)sidx[j] * LPN + lane];
#pragma unroll
        for (int j = 0; j < 8; j++) {
            acc.x = fmaf(wv[j], bflo(h[j].x), acc.x);
            acc.y = fmaf(wv[j], bfhi(h[j].x), acc.y);
            acc.z = fmaf(wv[j], bflo(h[j].y), acc.z);
            acc.w = fmaf(wv[j], bfhi(h[j].y), acc.w);
        }
    }

    const size_t oi = (size_t)node * LPN + lane;
    float4 r;
    if (MODE == 0) {
        float sc = dinv[node];   // invm passed via dinv arg
        r.x = acc.x * sc; r.y = acc.y * sc; r.z = acc.z * sc; r.w = acc.w * sc;
    } else {
        uint2 su = H2[oi];
        float s0 = bflo(su.x), s1 = bfhi(su.x), s2 = bflo(su.y), s3 = bfhi(su.y);
        float4 bv = ((const float4*)bias)[lane];
        if (MODE == 2) {
            float sw = den_[node];
            r.x = acc.x + sw * s0 + bv.x;
            r.y = acc.y + sw * s1 + bv.y;
            r.z = acc.z + sw * s2 + bv.z;
            r.w = acc.w + sw * s3 + bv.w;
            r.x = fmaxf(r.x, 0.f); r.y = fmaxf(r.y, 0.f);
            r.z = fmaxf(r.z, 0.f); r.w = fmaxf(r.w, 0.f);
        } else {
            float dv = dinv[node];
            r.x = dv * (acc.x + s0) + bv.x;
            r.y = dv * (acc.y + s1) + bv.y;
            r.z = dv * (acc.z + s2) + bv.z;
            r.w = dv * (acc.w + s3) + bv.w;
            if (MODE == 1) {
                r.x = fmaxf(r.x, 0.f); r.y = fmaxf(r.y, 0.f);
                r.z = fmaxf(r.z, 0.f); r.w = fmaxf(r.w, 0.f);
            }
        }
    }
    if (MODE == 3) {
        ((float4*)outf)[oi] = r;
    } else {
        ushort4 qv; qv.x = f2bf(r.x); qv.y = f2bf(r.y); qv.z = f2bf(r.z); qv.w = f2bf(r.w);
        ((ushort4*)out16)[oi] = qv;
    }
}

// ---------------- GAT attention dots from bf16 features ----------------
__global__ __launch_bounds__(256) void attn_dots16_k(
    const unsigned short* __restrict__ H16, const float* __restrict__ a_s,
    const float* __restrict__ a_d, float* __restrict__ as_,
    float* __restrict__ ad_, int n)
{
    int gid = blockIdx.x * 256 + threadIdx.x;
    int node = gid >> 6, lane = gid & 63;
    if (node >= n) return;
    unsigned u = *(const unsigned*)(H16 + (size_t)node * 128 + lane * 2);
    float v0 = bflo(u), v1 = bfhi(u);
    float s = v0 * a_s[2 * lane] + v1 * a_s[2 * lane + 1];
    float d = v0 * a_d[2 * lane] + v1 * a_d[2 * lane + 1];
    for (int off = 32; off > 0; off >>= 1) {
        s += __shfl_xor(s, off, 64);
        d += __shfl_xor(d, off, 64);
    }
    if (lane == 0) { as_[node] = s; ad_[node] = d; }
}

// ---------------- GAT softmax: recG[e]=(src,alpha), den_[node]=self-alpha ----
__global__ __launch_bounds__(256) void attn_reduce_k(
    const int* __restrict__ rowptr, const int* __restrict__ srcs,
    const float* __restrict__ as_, const float* __restrict__ ad_,
    uint2* __restrict__ recG, float* __restrict__ den_, int n)
{
    int node = blockIdx.x * 4 + (int)(threadIdx.x >> 6);
    int lane = threadIdx.x & 63;
    if (node >= n) return;
    int beg = rowptr[node], end = rowptr[node + 1];
    float ad_d = ad_[node];
    float self_e = leaky02(as_[node] + ad_d);
    float mx = self_e;
    for (int k = beg + lane; k < end; k += 64)
        mx = fmaxf(mx, leaky02(as_[srcs[k]] + ad_d));
    for (int off = 32; off > 0; off >>= 1) mx = fmaxf(mx, __shfl_xor(mx, off, 64));
    float sum = (lane == 0) ? expf(self_e - mx) : 0.0f;
    for (int k = beg + lane; k < end; k += 64)
        sum += expf(leaky02(as_[srcs[k]] + ad_d) - mx);
    for (int off = 32; off > 0; off >>= 1) sum += __shfl_xor(sum, off, 64);
    float rden = 1.0f / sum;
    for (int k = beg + lane; k < end; k += 64) {
        int s = srcs[k];
        float a = expf(leaky02(as_[s] + ad_d) - mx) * rden;
        recG[k] = make_uint2((unsigned)s, __float_as_uint(a));
    }
    if (lane == 0) den_[node] = expf(self_e - mx) * rden;
}

// ---------------------------------------------------------------------------
extern "C" void kernel_launch(void* const* d_in, const int* in_sizes, int n_in,
                              void* d_out, int out_size, void* d_ws, size_t ws_size,
                              hipStream_t stream)
{
    const float* x   = (const float*)d_in[0];
    const int*   ei  = (const int*)d_in[1];
    const float* W1  = (const float*)d_in[2];
    const float* b1  = (const float*)d_in[3];
    const float* Wl  = (const float*)d_in[4];
    const float* Wr  = (const float*)d_in[5];
    const float* bs  = (const float*)d_in[6];
    const float* Wg  = (const float*)d_in[7];
    const float* a_s = (const float*)d_in[8];
    const float* a_d = (const float*)d_in[9];
    const float* bg  = (const float*)d_in[10];
    const float* Wo  = (const float*)d_in[11];
    const float* bo  = (const float*)d_in[12];

    const int n  = in_sizes[0] / 128;
    const int nE = in_sizes[1] / 2;
    const int* src = ei;
    const int* dst = ei + nE;

    char* w = (char*)d_ws;
    auto alloc = [&](size_t bytes) { char* p = w; w += (bytes + 255) & ~(size_t)255; return p; };
    unsigned short* S0 = (unsigned short*)alloc((size_t)n * 128 * 2);
    unsigned short* S1 = (unsigned short*)alloc((size_t)n * 128 * 2);
    unsigned short* S2 = (unsigned short*)alloc((size_t)n * 128 * 2);
    unsigned long long* part = (unsigned long long*)alloc((size_t)nE * 8);
    int*   srcs   = (int*)alloc((size_t)nE * 4);
    uint2* recG   = (uint2*)alloc((size_t)nE * 8);
    int*   rowptr = (int*)alloc((size_t)(n + 1) * 4);
    int*   btot   = (int*)alloc(NBMAX * 4);
    int*   bofs   = (int*)alloc((NBMAX + 1) * 4);
    int*   bcur   = (int*)alloc(NBMAX * 4);
    float* dinv   = (float*)alloc((size_t)n * 4);
    float* invm   = (float*)alloc((size_t)n * 4);
    float* as_    = (float*)alloc((size_t)n * 4);
    float* ad_    = (float*)alloc((size_t)n * 4);
    float* den_   = (float*)alloc((size_t)n * 4);

    const int TB = 256;
    auto cdiv = [](long long a, long long b) { return (int)((a + b - 1) / b); };
    const int nb     = cdiv(n, BUCKET_SZ);
    const int gBh    = cdiv(nE, BH_CH);
    const int gPart  = cdiv(nE, PART_CH);
    const int gGemm  = cdiv(n, 64);
    const int gGa128 = cdiv(n, 8);
    const int gGa64  = cdiv(n, 16);
    const int gQuad  = cdiv(n, 4);
    const int gWave  = cdiv((long long)n * 64, TB);

    // ---- CSR build
    hipMemsetAsync(btot, 0, NBMAX * 4, stream);
    bhist_k<<<gBh, TB, 0, stream>>>(dst, btot, nE);
    bscan_k<<<1, 256, 0, stream>>>(btot, bofs, bcur, nb);
    part_k<<<gPart, TB, 0, stream>>>(src, dst, bcur, part, nE);
    csr_k<<<nb, TB, 0, stream>>>(part, bofs, rowptr, srcs, dinv, invm, n, nE);

    // ---- Layer 1: GCN — x@W1 scaled by dinv[row] -> S0; gather -> S1 (=h1)
    mgemm_k<128, true, true, false, false><<<gGemm, TB, 0, stream>>>(
        x, W1, nullptr, nullptr, S0, dinv, nullptr, n);
    gatherbf_k<128, 1><<<gGa128, TB, 0, stream>>>(S0, nullptr, S1, rowptr, srcs,
                                                  nullptr, dinv, nullptr, b1, n);

    // ---- Layer 2: SAGE — mean(S1) -> S0; dual GEMM mean@Wl + h1@Wr -> S2 (=h2)
    gatherbf_k<128, 0><<<gGa128, TB, 0, stream>>>(S1, nullptr, S0, rowptr, srcs,
                                                  nullptr, invm, nullptr, nullptr, n);
    mgemm_k<128, false, false, true, true><<<gGemm, TB, 0, stream>>>(
        S0, Wl, S1, Wr, S2, nullptr, bs, n);

    // ---- Layer 3: GAT — h2@Wg -> S1; dots; softmax; gather -> S0 (=h3)
    mgemm_k<128, false, false, false, false><<<gGemm, TB, 0, stream>>>(
        S2, Wg, nullptr, nullptr, S1, nullptr, nullptr, n);
    attn_dots16_k<<<gWave, TB, 0, stream>>>(S1, a_s, a_d, as_, ad_, n);
    attn_reduce_k<<<gQuad, TB, 0, stream>>>(rowptr, srcs, as_, ad_, recG, den_, n);
    gatherbf_k<128, 2><<<gGa128, TB, 0, stream>>>(S1, nullptr, S0, rowptr, srcs,
                                                  recG, nullptr, den_, bg, n);

    // ---- Output: h3@Wo scaled by dinv[row] -> S2; gather -> d_out (fp32)
    mgemm_k<64, false, true, false, false><<<gGemm, TB, 0, stream>>>(
        S0, Wo, nullptr, nullptr, S2, dinv, nullptr, n);
    gatherbf_k<64, 3><<<gGa64, TB, 0, stream>>>(S2, (float*)d_out, nullptr, rowptr, srcs,
                                                nullptr, dinv, nullptr, bo, n);
}